// Round 10
// baseline (619.119 us; speedup 1.0000x reference)
//
#include <hip/hip_runtime.h>
#include <hip/hip_bf16.h>

#define NN 50000
#define EE 640000
#define FF 128
#define HH 128

typedef unsigned short ushort_t;
typedef unsigned int   uint_t;
using f32x4  = __attribute__((ext_vector_type(4))) float;
using bf16x8 = __attribute__((ext_vector_type(8))) __bf16;
using u16x8  = __attribute__((ext_vector_type(8))) unsigned short;

__device__ __forceinline__ ushort_t f2bf(float f) {
    union { float f; unsigned int i; } v; v.f = f;
    unsigned int r = v.i + 0x7fffu + ((v.i >> 16) & 1u);
    return (ushort_t)(r >> 16);
}
__device__ __forceinline__ float bf2f(uint_t u) {
    union { uint_t i; float f; } v; v.i = u << 16; return v.f;
}
__device__ __forceinline__ float fsilu(float x) { return x / (1.f + __expf(-x)); }
__device__ __forceinline__ float fsig(float x)  { return 1.f / (1.f + __expf(-x)); }

__device__ __forceinline__ u16x8 cvt8(const float* p) {
    float4 a0 = *reinterpret_cast<const float4*>(p);
    float4 a1 = *reinterpret_cast<const float4*>(p + 4);
    u16x8 v;
    v[0] = f2bf(a0.x); v[1] = f2bf(a0.y); v[2] = f2bf(a0.z); v[3] = f2bf(a0.w);
    v[4] = f2bf(a1.x); v[5] = f2bf(a1.y); v[6] = f2bf(a1.z); v[7] = f2bf(a1.w);
    return v;
}

// ---------------------------------------------------------------------------
// prep: h f32->bf16  +  degree histogram (fused)
// ---------------------------------------------------------------------------
__global__ void prep_kernel(const float* __restrict__ h, ushort_t* __restrict__ hbf,
                            const int* __restrict__ eidx, int* __restrict__ deg)
{
    const int t = blockIdx.x * 256 + threadIdx.x;
    if (t * 8 < NN * 128) {
        u16x8 v = cvt8(h + (size_t)t * 8);
        *reinterpret_cast<u16x8*>(hbf + (size_t)t * 8) = v;
    }
    if (t < EE) atomicAdd(&deg[eidx[t]], 1);
}

__global__ void scan_kernel(const int* __restrict__ deg, int* __restrict__ row_ptr,
                            int* __restrict__ cursor)
{
    __shared__ int sdata[1024];
    const int t = threadIdx.x;
    const int chunk = (NN + 1023) / 1024;
    const int start = t * chunk;
    const int end   = min(start + chunk, NN);
    int s = 0;
    for (int i = start; i < end; ++i) s += deg[i];
    sdata[t] = s;
    __syncthreads();
    for (int off = 1; off < 1024; off <<= 1) {
        int v = (t >= off) ? sdata[t - off] : 0;
        __syncthreads();
        sdata[t] += v;
        __syncthreads();
    }
    int ox = sdata[t] - s;
    for (int i = start; i < end; ++i) {
        row_ptr[i] = ox; cursor[i] = ox; ox += deg[i];
    }
    if (t == 1023) row_ptr[NN] = sdata[1023];
}

__global__ void scatter_kernel(const int* __restrict__ eidx, int* __restrict__ cursor,
                               int* __restrict__ edge_list, int* __restrict__ row_sorted)
{
    const int e = blockIdx.x * 256 + threadIdx.x;
    if (e < EE) {
        const int r = eidx[e];
        const int p = atomicAdd(&cursor[r], 1);
        edge_list[p] = e;
        row_sorted[p] = r;
    }
}

// ---------------------------------------------------------------------------
// Edge kernel, 512 threads (8 waves), CSR-ordered 64-edge tiles, in-kernel
// aggregation. Wave w owns MFMA cols 16w..16w+15 and post-phase rows
// 8w..8w+7. LDS ~55KB -> 2 blocks/CU -> 16 waves/CU.
// ---------------------------------------------------------------------------
#define A_STR 288   // ushorts
#define M_STR 136   // ushorts

__device__ __forceinline__ ushort_t* a_ptr(ushort_t* base, int row, int b) {
    const int bs = (b < 512) ? (b ^ ((row & 7) << 4)) : b;
    return base + row * A_STR + (bs >> 1);
}

__global__ __launch_bounds__(512) void egcl_edge_kernel(
    const ushort_t* __restrict__ hbf, const float* __restrict__ pos,
    const int* __restrict__ eidx, const float* __restrict__ eattr,
    const int* __restrict__ edge_list, const int* __restrict__ row_sorted,
    const float* __restrict__ w1, const float* __restrict__ b1,
    const float* __restrict__ w2, const float* __restrict__ b2,
    const float* __restrict__ aW, const float* __restrict__ ab,
    const float* __restrict__ pW2,
    float* __restrict__ m_out, float* __restrict__ agg, float* __restrict__ agg_t)
{
    __shared__ __align__(16) ushort_t A_sh[64 * A_STR];   // 36,864 B
    __shared__ __align__(16) ushort_t M1_sh[64 * M_STR];  // 17,408 B
    __shared__ int   ROW_sh[64];
    __shared__ float GATE_sh[64];
    __shared__ float SP_sh[64];

    ushort_t* M2_sh = A_sh;   // [64][M_STR], dead-A alias

    const int tid  = threadIdx.x;
    const int lane = tid & 63;
    const int w    = tid >> 6;     // wave 0..7
    const int l15  = lane & 15;
    const int lg   = lane >> 4;

    // ---- weights in registers (per wave: cols 16w..16w+15) ----
    bf16x8 B1[9];
    bf16x8 B2[4];
    bf16x8 Bg[4];
    const int colg = 16 * w + l15;
    const float b1c = b1[colg];
    const float b2c = b2[colg];
    const float abv = ab[0];
#pragma unroll
    for (int ks = 0; ks < 9; ++ks) {
        u16x8 v;
#pragma unroll
        for (int j = 0; j < 8; ++j) {
            const int k = 32 * ks + 8 * lg + j;
            v[j] = (k < 265) ? f2bf(w1[k * 128 + colg]) : (ushort_t)0;
        }
        B1[ks] = __builtin_bit_cast(bf16x8, v);
    }
#pragma unroll
    for (int ks = 0; ks < 4; ++ks) {
        u16x8 v;
#pragma unroll
        for (int j = 0; j < 8; ++j) {
            const int k = 32 * ks + 8 * lg + j;
            v[j] = f2bf(w2[k * 128 + colg]);
        }
        B2[ks] = __builtin_bit_cast(bf16x8, v);
    }
#pragma unroll
    for (int ks = 0; ks < 4; ++ks) {
        u16x8 v;
#pragma unroll
        for (int j = 0; j < 8; ++j) {
            const int k = 32 * ks + 8 * lg + j;
            v[j] = (l15 == 0) ? f2bf(aW[k]) : (l15 == 1 ? f2bf(pW2[k]) : (ushort_t)0);
        }
        Bg[ks] = __builtin_bit_cast(bf16x8, v);
    }

    const int ei = tid >> 3;   // CSR slot 0..63
    const int et = tid & 7;    // 8 threads/slot, 16 bf16 each per region

    for (int tile = blockIdx.x; tile < EE / 64; tile += gridDim.x) {
        // ---- stage (CSR order; pd in regs on et==0 lanes) ----
        float pdx = 0.f, pdy = 0.f, pdz = 0.f;
        {
            const int p  = tile * 64 + ei;
            const int eo = edge_list[p];
            const int r  = row_sorted[p];
            const int c  = eidx[EE + eo];
            const ushort_t* hr = hbf + (size_t)r * 128 + et * 16;
            const ushort_t* hc = hbf + (size_t)c * 128 + et * 16;
#pragma unroll
            for (int q = 0; q < 2; ++q) {
                *reinterpret_cast<u16x8*>(a_ptr(A_sh, ei, 32 * et + 16 * q)) =
                    *reinterpret_cast<const u16x8*>(hr + q * 8);
                *reinterpret_cast<u16x8*>(a_ptr(A_sh, ei, 256 + 32 * et + 16 * q)) =
                    *reinterpret_cast<const u16x8*>(hc + q * 8);
            }
            if (et == 0) {
                ROW_sh[ei] = r;
                pdx = pos[r * 3 + 0] - pos[c * 3 + 0];
                pdy = pos[r * 3 + 1] - pos[c * 3 + 1];
                pdz = pos[r * 3 + 2] - pos[c * 3 + 2];
                const float ds = pdx * pdx + pdy * pdy + pdz * pdz;
                const float4 ea0 = *reinterpret_cast<const float4*>(eattr + (size_t)eo * 8);
                const float4 ea1 = *reinterpret_cast<const float4*>(eattr + (size_t)eo * 8 + 4);
                u16x8 v0;
                v0[0] = f2bf(ds);
                v0[1] = f2bf(ea0.x); v0[2] = f2bf(ea0.y); v0[3] = f2bf(ea0.z);
                v0[4] = f2bf(ea0.w); v0[5] = f2bf(ea1.x); v0[6] = f2bf(ea1.y);
                v0[7] = f2bf(ea1.z);
                *reinterpret_cast<u16x8*>(a_ptr(A_sh, ei, 512)) = v0;
                u16x8 v1 = {0, 0, 0, 0, 0, 0, 0, 0};
                v1[0] = f2bf(ea1.w);
                *reinterpret_cast<u16x8*>(a_ptr(A_sh, ei, 528)) = v1;
                u16x8 z = {0, 0, 0, 0, 0, 0, 0, 0};
                *reinterpret_cast<u16x8*>(a_ptr(A_sh, ei, 544)) = z;
                *reinterpret_cast<u16x8*>(a_ptr(A_sh, ei, 560)) = z;
            }
        }
        __syncthreads();                       // B1: A/ROW ready

        // ---- layer 1 (per wave: 16 cols, 4 subtiles x 9 MFMA) ----
#pragma unroll
        for (int s = 0; s < 4; ++s) {
            f32x4 a0 = {0.f, 0.f, 0.f, 0.f};
#pragma unroll
            for (int ks = 0; ks < 9; ++ks) {
                bf16x8 a = *reinterpret_cast<const bf16x8*>(
                    a_ptr(A_sh, 16 * s + l15, 64 * ks + 16 * lg));
                a0 = __builtin_amdgcn_mfma_f32_16x16x32_bf16(a, B1[ks], a0, 0, 0, 0);
            }
#pragma unroll
            for (int rr = 0; rr < 4; ++rr) {
                const float x = a0[rr] + b1c;
                const int edge = 16 * s + 4 * lg + rr;
                M1_sh[edge * M_STR + colg] = f2bf(fsilu(x));
            }
        }
        __syncthreads();                       // B2: M1 ready, A dead

        // ---- layer 2 -> M2 (bf16, dead-A alias) ----
#pragma unroll
        for (int s = 0; s < 4; ++s) {
            f32x4 a0 = {0.f, 0.f, 0.f, 0.f};
#pragma unroll
            for (int ks = 0; ks < 4; ++ks) {
                bf16x8 a = *reinterpret_cast<const bf16x8*>(
                    &M1_sh[(16 * s + l15) * M_STR + ks * 32 + lg * 8]);
                a0 = __builtin_amdgcn_mfma_f32_16x16x32_bf16(a, B2[ks], a0, 0, 0, 0);
            }
#pragma unroll
            for (int rr = 0; rr < 4; ++rr) {
                const float x = a0[rr] + b2c;
                const int edge = 16 * s + 4 * lg + rr;
                M2_sh[edge * M_STR + colg] = f2bf(fsilu(x));
            }
        }
        __syncthreads();                       // B3: M2 ready

        // ---- gate: waves 0..3 compute subtile w -> GATE_sh/SP_sh ----
        if (w < 4) {
            f32x4 ga = {0.f, 0.f, 0.f, 0.f};
#pragma unroll
            for (int ks = 0; ks < 4; ++ks) {
                bf16x8 a = *reinterpret_cast<const bf16x8*>(
                    &M2_sh[(16 * w + l15) * M_STR + ks * 32 + lg * 8]);
                ga = __builtin_amdgcn_mfma_f32_16x16x32_bf16(a, Bg[ks], ga, 0, 0, 0);
            }
#pragma unroll
            for (int rr = 0; rr < 4; ++rr) {
                const float sa = __shfl(ga[rr], lane & 48);
                const float sp = __shfl(ga[rr], (lane & 48) + 1);
                if (l15 == 0) {
                    const int edge = 16 * w + 4 * lg + rr;
                    GATE_sh[edge] = fsig(sa + abv);
                    SP_sh[edge]   = sp;
                }
            }
        }
        __syncthreads();                       // B4: GATE/SP visible

        // ---- coalesced gated m_out: wave w owns rows 8w..8w+7 ----
#pragma unroll
        for (int j = 0; j < 8; ++j) {
            const int row = 8 * w + j;
            const int eo  = edge_list[tile * 64 + row];
            const uint_t pv = *reinterpret_cast<const uint_t*>(&M2_sh[row * M_STR + 2 * lane]);
            const float g = GATE_sh[row];
            float2 st;
            st.x = bf2f(pv & 0xffffu) * g;
            st.y = bf2f(pv >> 16) * g;
            *reinterpret_cast<float2*>(&m_out[(size_t)eo * 128 + 2 * lane]) = st;
        }

        // ---- trans: wave w flushes its 8 edges (pd via shfl, segmented) ----
        {
            float px[8], py[8], pz[8];
#pragma unroll
            for (int j = 0; j < 8; ++j) {
                px[j] = __shfl(pdx, 8 * j);
                py[j] = __shfl(pdy, 8 * j);
                pz[j] = __shfl(pdz, 8 * j);
            }
            if (lane == 0) {
                int cur = -1; float t0 = 0.f, t1 = 0.f, t2 = 0.f;
#pragma unroll
                for (int j = 0; j < 8; ++j) {
                    const int e = 8 * w + j;
                    const int rid = ROW_sh[e];
                    const float t = GATE_sh[e] * SP_sh[e];
                    if (rid != cur) {
                        if (cur >= 0) {
                            atomicAdd(&agg_t[cur * 3 + 0], t0);
                            atomicAdd(&agg_t[cur * 3 + 1], t1);
                            atomicAdd(&agg_t[cur * 3 + 2], t2);
                        }
                        cur = rid; t0 = t1 = t2 = 0.f;
                    }
                    t0 += px[j] * t; t1 += py[j] * t; t2 += pz[j] * t;
                }
                atomicAdd(&agg_t[cur * 3 + 0], t0);
                atomicAdd(&agg_t[cur * 3 + 1], t1);
                atomicAdd(&agg_t[cur * 3 + 2], t2);
            }
        }

        // ---- segmented column scan: 4 segments x 16 rows ----
        {
            const int col = tid & 127;
            const int j0  = (tid >> 7) * 16;
            int cur = ROW_sh[j0];
            float acc = 0.f;
#pragma unroll 4
            for (int j = j0; j < j0 + 16; ++j) {
                const int rid = ROW_sh[j];
                const float v = bf2f((uint_t)M2_sh[j * M_STR + col]) * GATE_sh[j];
                if (rid != cur) {
                    atomicAdd(&agg[(size_t)cur * 128 + col], acc);
                    acc = 0.f; cur = rid;
                }
                acc += v;
            }
            atomicAdd(&agg[(size_t)cur * 128 + col], acc);
        }
        __syncthreads();                       // B5: protect LDS for next tile
    }
}

// ---------------------------------------------------------------------------
// Node kernel: streaming. h_new = silu([hbf|bf16(agg)]@nW1+nb1)@nW2+nb2+h,
// pos_new = pos + agg_t / max(deg,1)  (deg from row_ptr diff)
// ---------------------------------------------------------------------------
__global__ __launch_bounds__(256, 4) void egcl_node_kernel(
    const ushort_t* __restrict__ hbf, const float* __restrict__ h,
    const float* __restrict__ agg, const float* __restrict__ agg_t,
    const int* __restrict__ row_ptr, const float* __restrict__ pos,
    const float* __restrict__ w1, const float* __restrict__ b1,
    const float* __restrict__ w2, const float* __restrict__ b2,
    float* __restrict__ hn_out, float* __restrict__ pos_out)
{
    __shared__ __align__(16) ushort_t A_sh[16 * 264];
    __shared__ __align__(16) ushort_t M1_sh[16 * 136];

    const int tid  = threadIdx.x;
    const int lane = tid & 63;
    const int w    = tid >> 6;
    const int l15  = lane & 15;
    const int lg   = lane >> 4;

    bf16x8 B1[8][2];
    bf16x8 B2[4][2];
    float b1c[2], b2c[2];
#pragma unroll
    for (int nt = 0; nt < 2; ++nt) {
        const int colg = 32 * w + 16 * nt + l15;
        b1c[nt] = b1[colg];
        b2c[nt] = b2[colg];
#pragma unroll
        for (int ks = 0; ks < 8; ++ks) {
            u16x8 v;
#pragma unroll
            for (int j = 0; j < 8; ++j) {
                const int k = 32 * ks + 8 * lg + j;
                v[j] = f2bf(w1[k * 128 + colg]);
            }
            B1[ks][nt] = __builtin_bit_cast(bf16x8, v);
        }
#pragma unroll
        for (int ks = 0; ks < 4; ++ks) {
            u16x8 v;
#pragma unroll
            for (int j = 0; j < 8; ++j) {
                const int k = 32 * ks + 8 * lg + j;
                v[j] = f2bf(w2[k * 128 + colg]);
            }
            B2[ks][nt] = __builtin_bit_cast(bf16x8, v);
        }
    }

    const int ni = tid >> 4;
    const int nt16 = tid & 15;

    for (int tile = blockIdx.x; tile < NN / 16; tile += gridDim.x) {
        __syncthreads();
        const int base = tile * 16;
        {
            const size_t n = (size_t)base + ni;
            *reinterpret_cast<u16x8*>(&A_sh[ni * 264 + nt16 * 8]) =
                *reinterpret_cast<const u16x8*>(hbf + n * 128 + nt16 * 8);
            u16x8 av = cvt8(agg + n * 128 + nt16 * 8);
            *reinterpret_cast<u16x8*>(&A_sh[ni * 264 + 128 + nt16 * 8]) = av;
        }
        if (tid < 48) {
            const int nl = tid / 3, d = tid % 3;
            const size_t n = (size_t)base + nl;
            const float c = (float)(row_ptr[n + 1] - row_ptr[n]);
            pos_out[n * 3 + d] = pos[n * 3 + d] + agg_t[n * 3 + d] / fmaxf(c, 1.f);
        }
        __syncthreads();

        f32x4 acc10 = {0.f, 0.f, 0.f, 0.f};
        f32x4 acc11 = {0.f, 0.f, 0.f, 0.f};
#pragma unroll
        for (int ks = 0; ks < 8; ++ks) {
            bf16x8 a = *reinterpret_cast<const bf16x8*>(&A_sh[l15 * 264 + ks * 32 + lg * 8]);
            acc10 = __builtin_amdgcn_mfma_f32_16x16x32_bf16(a, B1[ks][0], acc10, 0, 0, 0);
            acc11 = __builtin_amdgcn_mfma_f32_16x16x32_bf16(a, B1[ks][1], acc11, 0, 0, 0);
        }
#pragma unroll
        for (int nt = 0; nt < 2; ++nt) {
#pragma unroll
            for (int r = 0; r < 4; ++r) {
                const float x = (nt == 0 ? acc10[r] : acc11[r]) + b1c[nt];
                const int nl = 4 * lg + r;
                const int colg = 32 * w + 16 * nt + l15;
                M1_sh[nl * 136 + colg] = f2bf(fsilu(x));
            }
        }
        __syncthreads();

        f32x4 acc20 = {0.f, 0.f, 0.f, 0.f};
        f32x4 acc21 = {0.f, 0.f, 0.f, 0.f};
#pragma unroll
        for (int ks = 0; ks < 4; ++ks) {
            bf16x8 a = *reinterpret_cast<const bf16x8*>(&M1_sh[l15 * 136 + ks * 32 + lg * 8]);
            acc20 = __builtin_amdgcn_mfma_f32_16x16x32_bf16(a, B2[ks][0], acc20, 0, 0, 0);
            acc21 = __builtin_amdgcn_mfma_f32_16x16x32_bf16(a, B2[ks][1], acc21, 0, 0, 0);
        }
#pragma unroll
        for (int nt = 0; nt < 2; ++nt) {
#pragma unroll
            for (int r = 0; r < 4; ++r) {
                const int nl = 4 * lg + r;
                const int colg = 32 * w + 16 * nt + l15;
                const size_t n = (size_t)base + nl;
                const float hres = h[n * 128 + colg];
                const float y = (nt == 0 ? acc20[r] : acc21[r]) + b2c[nt] + hres;
                hn_out[n * 128 + colg] = y;
            }
        }
    }
}

extern "C" void kernel_launch(void* const* d_in, const int* in_sizes, int n_in,
                              void* d_out, int out_size, void* d_ws, size_t ws_size,
                              hipStream_t stream)
{
    const float* h     = (const float*)d_in[0];
    const float* pos   = (const float*)d_in[1];
    const int*   eidx  = (const int*)d_in[2];
    const float* eattr = (const float*)d_in[3];
    const float* eW1   = (const float*)d_in[4];
    const float* eb1   = (const float*)d_in[5];
    const float* eW2   = (const float*)d_in[6];
    const float* eb2   = (const float*)d_in[7];
    const float* aW    = (const float*)d_in[8];
    const float* ab    = (const float*)d_in[9];
    const float* nW1   = (const float*)d_in[10];
    const float* nb1   = (const float*)d_in[11];
    const float* nW2   = (const float*)d_in[12];
    const float* nb2   = (const float*)d_in[13];
    const float* pW2   = (const float*)d_in[14];

    float* out    = (float*)d_out;
    float* hn_out = out;                                   // N*128
    float* po_out = out + (size_t)NN * 128;                // N*3
    float* m_out  = po_out + (size_t)NN * 3;               // E*128

    // ws layout (bytes)
    char* wsb = (char*)d_ws;
    float* agg        = (float*)(wsb + 0);                 // 25,600,000
    float* agg_t      = (float*)(wsb + 25600000);          //    600,000
    int*   deg        = (int*)  (wsb + 26200000);          //    200,000
    int*   row_ptr    = (int*)  (wsb + 26400000);          //    200,004
    int*   cursor     = (int*)  (wsb + 26600256);          //    200,000
    int*   edge_list  = (int*)  (wsb + 26800256);          //  2,560,000
    int*   row_sorted = (int*)  (wsb + 29360256);          //  2,560,000
    ushort_t* hbf     = (ushort_t*)(wsb + 31920256);       // 12,800,000

    // zero agg + agg_t + deg (contiguous)
    hipMemsetAsync(wsb, 0, 26400000, stream);

    prep_kernel<<<3200, 256, 0, stream>>>(h, hbf, eidx, deg);
    scan_kernel<<<1, 1024, 0, stream>>>(deg, row_ptr, cursor);
    scatter_kernel<<<(EE + 255) / 256, 256, 0, stream>>>(eidx, cursor, edge_list, row_sorted);

    egcl_edge_kernel<<<512, 512, 0, stream>>>(hbf, pos, eidx, eattr,
                                              edge_list, row_sorted,
                                              eW1, eb1, eW2, eb2, aW, ab, pW2,
                                              m_out, agg, agg_t);
    egcl_node_kernel<<<1024, 256, 0, stream>>>(hbf, h, agg, agg_t, row_ptr, pos,
                                               nW1, nb1, nW2, nb2,
                                               hn_out, po_out);
}

// Round 11
// 588.388 us; speedup vs baseline: 1.0522x; 1.0522x over previous
//
#include <hip/hip_runtime.h>
#include <hip/hip_bf16.h>

#define NN 50000
#define EE 640000
#define FF 128
#define HH 128

typedef unsigned short ushort_t;
typedef unsigned int   uint_t;
using f32x4  = __attribute__((ext_vector_type(4))) float;
using bf16x8 = __attribute__((ext_vector_type(8))) __bf16;
using u16x8  = __attribute__((ext_vector_type(8))) unsigned short;

__device__ __forceinline__ ushort_t f2bf(float f) {
    union { float f; unsigned int i; } v; v.f = f;
    unsigned int r = v.i + 0x7fffu + ((v.i >> 16) & 1u);
    return (ushort_t)(r >> 16);
}
__device__ __forceinline__ float bf2f(uint_t u) {
    union { uint_t i; float f; } v; v.i = u << 16; return v.f;
}
__device__ __forceinline__ float fsilu(float x) { return x / (1.f + __expf(-x)); }
__device__ __forceinline__ float fsig(float x)  { return 1.f / (1.f + __expf(-x)); }

__device__ __forceinline__ u16x8 cvt8(const float* p) {
    float4 a0 = *reinterpret_cast<const float4*>(p);
    float4 a1 = *reinterpret_cast<const float4*>(p + 4);
    u16x8 v;
    v[0] = f2bf(a0.x); v[1] = f2bf(a0.y); v[2] = f2bf(a0.z); v[3] = f2bf(a0.w);
    v[4] = f2bf(a1.x); v[5] = f2bf(a1.y); v[6] = f2bf(a1.z); v[7] = f2bf(a1.w);
    return v;
}

// ---------------------------------------------------------------------------
// prep: h f32->bf16  +  degree histogram (fused)
// ---------------------------------------------------------------------------
__global__ void prep_kernel(const float* __restrict__ h, ushort_t* __restrict__ hbf,
                            const int* __restrict__ eidx, int* __restrict__ deg)
{
    const int t = blockIdx.x * 256 + threadIdx.x;
    if (t * 8 < NN * 128) {
        u16x8 v = cvt8(h + (size_t)t * 8);
        *reinterpret_cast<u16x8*>(hbf + (size_t)t * 8) = v;
    }
    if (t < EE) atomicAdd(&deg[eidx[t]], 1);
}

__global__ void scan_kernel(const int* __restrict__ deg, int* __restrict__ row_ptr,
                            int* __restrict__ cursor)
{
    __shared__ int sdata[1024];
    const int t = threadIdx.x;
    const int chunk = (NN + 1023) / 1024;
    const int start = t * chunk;
    const int end   = min(start + chunk, NN);
    int s = 0;
    for (int i = start; i < end; ++i) s += deg[i];
    sdata[t] = s;
    __syncthreads();
    for (int off = 1; off < 1024; off <<= 1) {
        int v = (t >= off) ? sdata[t - off] : 0;
        __syncthreads();
        sdata[t] += v;
        __syncthreads();
    }
    int ox = sdata[t] - s;
    for (int i = start; i < end; ++i) {
        row_ptr[i] = ox; cursor[i] = ox; ox += deg[i];
    }
    if (t == 1023) row_ptr[NN] = sdata[1023];
}

__global__ void scatter_kernel(const int* __restrict__ eidx, int* __restrict__ cursor,
                               int* __restrict__ edge_list, int* __restrict__ row_sorted)
{
    const int e = blockIdx.x * 256 + threadIdx.x;
    if (e < EE) {
        const int r = eidx[e];
        const int p = atomicAdd(&cursor[r], 1);
        edge_list[p] = e;
        row_sorted[p] = r;
    }
}

// ---------------------------------------------------------------------------
// Edge kernel, 256 threads, CSR-ordered 64-edge tiles, in-kernel aggregation.
// LDS: A(64 x 544B, swz) + M1(64x136) + ROW/GATE/SP = 52,992 B
//   -> alloc 53,248 -> 3 blocks/CU (VGPR ~128 <= 170).
// A rows are 544B: 512B h-pair (swizzled) + 32B misc (K cols 256..271).
// K cols 272..287 are implicit zeros (B-fragments are zeroed there), so the
// ks==8 MFMA uses a literal zero A-fragment for lg>=2.
// M2 aliases dead-A. PD in staging-lane registers (+shfl). 5 barriers/tile.
// ---------------------------------------------------------------------------
#define A_STR 272   // ushorts (544 B)
#define M_STR 136   // ushorts (272 B)

__device__ __forceinline__ ushort_t* a_ptr(ushort_t* base, int row, int b) {
    const int bs = (b < 512) ? (b ^ ((row & 7) << 4)) : b;
    return base + row * A_STR + (bs >> 1);
}

__global__ __launch_bounds__(256, 2) void egcl_edge_kernel(
    const ushort_t* __restrict__ hbf, const float* __restrict__ pos,
    const int* __restrict__ eidx, const float* __restrict__ eattr,
    const int* __restrict__ edge_list, const int* __restrict__ row_sorted,
    const float* __restrict__ w1, const float* __restrict__ b1,
    const float* __restrict__ w2, const float* __restrict__ b2,
    const float* __restrict__ aW, const float* __restrict__ ab,
    const float* __restrict__ pW2,
    float* __restrict__ m_out, float* __restrict__ agg, float* __restrict__ agg_t)
{
    __shared__ __align__(16) ushort_t A_sh[64 * A_STR];   // 34,816 B
    __shared__ __align__(16) ushort_t M1_sh[64 * M_STR];  // 17,408 B
    __shared__ int   ROW_sh[64];
    __shared__ float GATE_sh[64];
    __shared__ float SP_sh[64];

    ushort_t* M2_sh = A_sh;   // [64][M_STR], dead-A alias (17,408 <= 34,816)

    const int tid  = threadIdx.x;
    const int lane = tid & 63;
    const int w    = tid >> 6;
    const int l15  = lane & 15;
    const int lg   = lane >> 4;

    // ---- weights in registers (per wave: cols 32w..32w+31) ----
    bf16x8 B1[9][2];
    bf16x8 B2[4][2];
    bf16x8 Bg[4];
    float b1c[2], b2c[2];
    const float abv = ab[0];
#pragma unroll
    for (int nt = 0; nt < 2; ++nt) {
        const int colg = 32 * w + 16 * nt + l15;
        b1c[nt] = b1[colg];
        b2c[nt] = b2[colg];
#pragma unroll
        for (int ks = 0; ks < 9; ++ks) {
            u16x8 v;
#pragma unroll
            for (int j = 0; j < 8; ++j) {
                const int k = 32 * ks + 8 * lg + j;
                v[j] = (k < 265) ? f2bf(w1[k * 128 + colg]) : (ushort_t)0;
            }
            B1[ks][nt] = __builtin_bit_cast(bf16x8, v);
        }
#pragma unroll
        for (int ks = 0; ks < 4; ++ks) {
            u16x8 v;
#pragma unroll
            for (int j = 0; j < 8; ++j) {
                const int k = 32 * ks + 8 * lg + j;
                v[j] = f2bf(w2[k * 128 + colg]);
            }
            B2[ks][nt] = __builtin_bit_cast(bf16x8, v);
        }
    }
#pragma unroll
    for (int ks = 0; ks < 4; ++ks) {
        u16x8 v;
#pragma unroll
        for (int j = 0; j < 8; ++j) {
            const int k = 32 * ks + 8 * lg + j;
            v[j] = (l15 == 0) ? f2bf(aW[k]) : (l15 == 1 ? f2bf(pW2[k]) : (ushort_t)0);
        }
        Bg[ks] = __builtin_bit_cast(bf16x8, v);
    }

    const int ei = tid >> 2;   // CSR slot 0..63
    const int et = tid & 3;

    for (int tile = blockIdx.x; tile < EE / 64; tile += gridDim.x) {
        // ---- stage (CSR order; pd in regs on et==0 lanes) ----
        float pdx = 0.f, pdy = 0.f, pdz = 0.f;
        {
            const int p  = tile * 64 + ei;
            const int eo = edge_list[p];
            const int r  = row_sorted[p];
            const int c  = eidx[EE + eo];
            const ushort_t* hr = hbf + (size_t)r * 128 + et * 32;
            const ushort_t* hc = hbf + (size_t)c * 128 + et * 32;
#pragma unroll
            for (int q = 0; q < 4; ++q) {
                *reinterpret_cast<u16x8*>(a_ptr(A_sh, ei, 64 * et + 16 * q)) =
                    *reinterpret_cast<const u16x8*>(hr + q * 8);
                *reinterpret_cast<u16x8*>(a_ptr(A_sh, ei, 256 + 64 * et + 16 * q)) =
                    *reinterpret_cast<const u16x8*>(hc + q * 8);
            }
            if (et == 0) {
                ROW_sh[ei] = r;
                pdx = pos[r * 3 + 0] - pos[c * 3 + 0];
                pdy = pos[r * 3 + 1] - pos[c * 3 + 1];
                pdz = pos[r * 3 + 2] - pos[c * 3 + 2];
                const float ds = pdx * pdx + pdy * pdy + pdz * pdz;
                const float4 ea0 = *reinterpret_cast<const float4*>(eattr + (size_t)eo * 8);
                const float4 ea1 = *reinterpret_cast<const float4*>(eattr + (size_t)eo * 8 + 4);
                u16x8 v0;
                v0[0] = f2bf(ds);
                v0[1] = f2bf(ea0.x); v0[2] = f2bf(ea0.y); v0[3] = f2bf(ea0.z);
                v0[4] = f2bf(ea0.w); v0[5] = f2bf(ea1.x); v0[6] = f2bf(ea1.y);
                v0[7] = f2bf(ea1.z);
                *reinterpret_cast<u16x8*>(a_ptr(A_sh, ei, 512)) = v0;
                u16x8 v1 = {0, 0, 0, 0, 0, 0, 0, 0};
                v1[0] = f2bf(ea1.w);
                *reinterpret_cast<u16x8*>(a_ptr(A_sh, ei, 528)) = v1;
            }
        }
        __syncthreads();                       // B1: A/ROW ready

        // ---- layer 1 ----
#pragma unroll
        for (int s = 0; s < 4; ++s) {
            f32x4 a0 = {0.f, 0.f, 0.f, 0.f};
            f32x4 a1 = {0.f, 0.f, 0.f, 0.f};
#pragma unroll
            for (int ks = 0; ks < 9; ++ks) {
                bf16x8 a;
                if (ks < 8 || lg < 2) {
                    a = *reinterpret_cast<const bf16x8*>(
                        a_ptr(A_sh, 16 * s + l15, 64 * ks + 16 * lg));
                } else {
                    u16x8 z = {0, 0, 0, 0, 0, 0, 0, 0};
                    a = __builtin_bit_cast(bf16x8, z);   // K cols 272..287: B is 0 too
                }
                a0 = __builtin_amdgcn_mfma_f32_16x16x32_bf16(a, B1[ks][0], a0, 0, 0, 0);
                a1 = __builtin_amdgcn_mfma_f32_16x16x32_bf16(a, B1[ks][1], a1, 0, 0, 0);
            }
#pragma unroll
            for (int nt = 0; nt < 2; ++nt) {
#pragma unroll
                for (int rr = 0; rr < 4; ++rr) {
                    const float x = (nt == 0 ? a0[rr] : a1[rr]) + b1c[nt];
                    const int edge = 16 * s + 4 * lg + rr;
                    const int colg = 32 * w + 16 * nt + l15;
                    M1_sh[edge * M_STR + colg] = f2bf(fsilu(x));
                }
            }
        }
        __syncthreads();                       // B2: M1 ready, A dead

        // ---- layer 2 -> M2 (bf16, dead-A alias) ----
#pragma unroll
        for (int s = 0; s < 4; ++s) {
            f32x4 a0 = {0.f, 0.f, 0.f, 0.f};
            f32x4 a1 = {0.f, 0.f, 0.f, 0.f};
#pragma unroll
            for (int ks = 0; ks < 4; ++ks) {
                bf16x8 a = *reinterpret_cast<const bf16x8*>(
                    &M1_sh[(16 * s + l15) * M_STR + ks * 32 + lg * 8]);
                a0 = __builtin_amdgcn_mfma_f32_16x16x32_bf16(a, B2[ks][0], a0, 0, 0, 0);
                a1 = __builtin_amdgcn_mfma_f32_16x16x32_bf16(a, B2[ks][1], a1, 0, 0, 0);
            }
#pragma unroll
            for (int nt = 0; nt < 2; ++nt) {
#pragma unroll
                for (int rr = 0; rr < 4; ++rr) {
                    const float x = (nt == 0 ? a0[rr] : a1[rr]) + b2c[nt];
                    const int edge = 16 * s + 4 * lg + rr;
                    const int colg = 32 * w + 16 * nt + l15;
                    M2_sh[edge * M_STR + colg] = f2bf(fsilu(x));
                }
            }
        }
        __syncthreads();                       // B3: M2 ready

        // ---- gate: own subtile (4 MFMA) -> GATE/SP + trans flush ----
        {
            f32x4 ga = {0.f, 0.f, 0.f, 0.f};
#pragma unroll
            for (int ks = 0; ks < 4; ++ks) {
                bf16x8 a = *reinterpret_cast<const bf16x8*>(
                    &M2_sh[(16 * w + l15) * M_STR + ks * 32 + lg * 8]);
                ga = __builtin_amdgcn_mfma_f32_16x16x32_bf16(a, Bg[ks], ga, 0, 0, 0);
            }
            float gqw[4], txw[4], tyw[4], tzw[4];
#pragma unroll
            for (int rr = 0; rr < 4; ++rr) {
                const float sa = __shfl(ga[rr], lane & 48);
                const float sp = __shfl(ga[rr], (lane & 48) + 1);
                gqw[rr] = fsig(sa + abv);
                const float t = gqw[rr] * sp;
                const float px = __shfl(pdx, 16 * lg + 4 * rr);
                const float py = __shfl(pdy, 16 * lg + 4 * rr);
                const float pz = __shfl(pdz, 16 * lg + 4 * rr);
                txw[rr] = px * t; tyw[rr] = py * t; tzw[rr] = pz * t;
                if (l15 == 0) GATE_sh[16 * w + 4 * lg + rr] = gqw[rr];
            }
            if (l15 == 0) {
                int cur = -1; float t0 = 0.f, t1 = 0.f, t2 = 0.f;
#pragma unroll
                for (int rr = 0; rr < 4; ++rr) {
                    const int rid = ROW_sh[16 * w + 4 * lg + rr];
                    if (rid != cur) {
                        if (cur >= 0) {
                            atomicAdd(&agg_t[cur * 3 + 0], t0);
                            atomicAdd(&agg_t[cur * 3 + 1], t1);
                            atomicAdd(&agg_t[cur * 3 + 2], t2);
                        }
                        cur = rid; t0 = t1 = t2 = 0.f;
                    }
                    t0 += txw[rr]; t1 += tyw[rr]; t2 += tzw[rr];
                }
                atomicAdd(&agg_t[cur * 3 + 0], t0);
                atomicAdd(&agg_t[cur * 3 + 1], t1);
                atomicAdd(&agg_t[cur * 3 + 2], t2);
            }
        }
        __syncthreads();                       // B4: GATE_sh visible

        // ---- coalesced gated m_out: wave w owns rows 16w..16w+15 ----
#pragma unroll
        for (int j = 0; j < 16; ++j) {
            const int row = 16 * w + j;
            const int eo  = edge_list[tile * 64 + row];
            const uint_t pv = *reinterpret_cast<const uint_t*>(&M2_sh[row * M_STR + 2 * lane]);
            const float g = GATE_sh[row];
            float2 st;
            st.x = bf2f(pv & 0xffffu) * g;
            st.y = bf2f(pv >> 16) * g;
            *reinterpret_cast<float2*>(&m_out[(size_t)eo * 128 + 2 * lane]) = st;
        }

        // ---- segmented column scan: agg[row] += gated m sums ----
        {
            const int col = tid & 127;
            const int j0  = (tid >> 7) * 32;
            int cur = ROW_sh[j0];
            float acc = 0.f;
#pragma unroll 4
            for (int j = j0; j < j0 + 32; ++j) {
                const int rid = ROW_sh[j];
                const float v = bf2f((uint_t)M2_sh[j * M_STR + col]) * GATE_sh[j];
                if (rid != cur) {
                    atomicAdd(&agg[(size_t)cur * 128 + col], acc);
                    acc = 0.f; cur = rid;
                }
                acc += v;
            }
            atomicAdd(&agg[(size_t)cur * 128 + col], acc);
        }
        __syncthreads();                       // B5: protect LDS for next tile
    }
}

// ---------------------------------------------------------------------------
// Node kernel: streaming. h_new = silu([hbf|bf16(agg)]@nW1+nb1)@nW2+nb2+h,
// residual read from LDS (bf16). pos_new = pos + agg_t / max(deg,1).
// ---------------------------------------------------------------------------
__global__ __launch_bounds__(256, 4) void egcl_node_kernel(
    const ushort_t* __restrict__ hbf,
    const float* __restrict__ agg, const float* __restrict__ agg_t,
    const int* __restrict__ row_ptr, const float* __restrict__ pos,
    const float* __restrict__ w1, const float* __restrict__ b1,
    const float* __restrict__ w2, const float* __restrict__ b2,
    float* __restrict__ hn_out, float* __restrict__ pos_out)
{
    __shared__ __align__(16) ushort_t A_sh[16 * 264];
    __shared__ __align__(16) ushort_t M1_sh[16 * 136];

    const int tid  = threadIdx.x;
    const int lane = tid & 63;
    const int w    = tid >> 6;
    const int l15  = lane & 15;
    const int lg   = lane >> 4;

    bf16x8 B1[8][2];
    bf16x8 B2[4][2];
    float b1c[2], b2c[2];
#pragma unroll
    for (int nt = 0; nt < 2; ++nt) {
        const int colg = 32 * w + 16 * nt + l15;
        b1c[nt] = b1[colg];
        b2c[nt] = b2[colg];
#pragma unroll
        for (int ks = 0; ks < 8; ++ks) {
            u16x8 v;
#pragma unroll
            for (int j = 0; j < 8; ++j) {
                const int k = 32 * ks + 8 * lg + j;
                v[j] = f2bf(w1[k * 128 + colg]);
            }
            B1[ks][nt] = __builtin_bit_cast(bf16x8, v);
        }
#pragma unroll
        for (int ks = 0; ks < 4; ++ks) {
            u16x8 v;
#pragma unroll
            for (int j = 0; j < 8; ++j) {
                const int k = 32 * ks + 8 * lg + j;
                v[j] = f2bf(w2[k * 128 + colg]);
            }
            B2[ks][nt] = __builtin_bit_cast(bf16x8, v);
        }
    }

    const int ni = tid >> 4;
    const int nt16 = tid & 15;

    for (int tile = blockIdx.x; tile < NN / 16; tile += gridDim.x) {
        __syncthreads();
        const int base = tile * 16;
        {
            const size_t n = (size_t)base + ni;
            *reinterpret_cast<u16x8*>(&A_sh[ni * 264 + nt16 * 8]) =
                *reinterpret_cast<const u16x8*>(hbf + n * 128 + nt16 * 8);
            u16x8 av = cvt8(agg + n * 128 + nt16 * 8);
            *reinterpret_cast<u16x8*>(&A_sh[ni * 264 + 128 + nt16 * 8]) = av;
        }
        if (tid < 48) {
            const int nl = tid / 3, d = tid % 3;
            const size_t n = (size_t)base + nl;
            const float c = (float)(row_ptr[n + 1] - row_ptr[n]);
            pos_out[n * 3 + d] = pos[n * 3 + d] + agg_t[n * 3 + d] / fmaxf(c, 1.f);
        }
        __syncthreads();

        f32x4 acc10 = {0.f, 0.f, 0.f, 0.f};
        f32x4 acc11 = {0.f, 0.f, 0.f, 0.f};
#pragma unroll
        for (int ks = 0; ks < 8; ++ks) {
            bf16x8 a = *reinterpret_cast<const bf16x8*>(&A_sh[l15 * 264 + ks * 32 + lg * 8]);
            acc10 = __builtin_amdgcn_mfma_f32_16x16x32_bf16(a, B1[ks][0], acc10, 0, 0, 0);
            acc11 = __builtin_amdgcn_mfma_f32_16x16x32_bf16(a, B1[ks][1], acc11, 0, 0, 0);
        }
#pragma unroll
        for (int nt = 0; nt < 2; ++nt) {
#pragma unroll
            for (int r = 0; r < 4; ++r) {
                const float x = (nt == 0 ? acc10[r] : acc11[r]) + b1c[nt];
                const int nl = 4 * lg + r;
                const int colg = 32 * w + 16 * nt + l15;
                M1_sh[nl * 136 + colg] = f2bf(fsilu(x));
            }
        }
        __syncthreads();

        f32x4 acc20 = {0.f, 0.f, 0.f, 0.f};
        f32x4 acc21 = {0.f, 0.f, 0.f, 0.f};
#pragma unroll
        for (int ks = 0; ks < 4; ++ks) {
            bf16x8 a = *reinterpret_cast<const bf16x8*>(&M1_sh[l15 * 136 + ks * 32 + lg * 8]);
            acc20 = __builtin_amdgcn_mfma_f32_16x16x32_bf16(a, B2[ks][0], acc20, 0, 0, 0);
            acc21 = __builtin_amdgcn_mfma_f32_16x16x32_bf16(a, B2[ks][1], acc21, 0, 0, 0);
        }
#pragma unroll
        for (int nt = 0; nt < 2; ++nt) {
#pragma unroll
            for (int r = 0; r < 4; ++r) {
                const int nl = 4 * lg + r;
                const int colg = 32 * w + 16 * nt + l15;
                const size_t n = (size_t)base + nl;
                const float hres = bf2f((uint_t)A_sh[nl * 264 + colg]);  // bf16 residual
                const float y = (nt == 0 ? acc20[r] : acc21[r]) + b2c[nt] + hres;
                hn_out[n * 128 + colg] = y;
            }
        }
    }
}

extern "C" void kernel_launch(void* const* d_in, const int* in_sizes, int n_in,
                              void* d_out, int out_size, void* d_ws, size_t ws_size,
                              hipStream_t stream)
{
    const float* h     = (const float*)d_in[0];
    const float* pos   = (const float*)d_in[1];
    const int*   eidx  = (const int*)d_in[2];
    const float* eattr = (const float*)d_in[3];
    const float* eW1   = (const float*)d_in[4];
    const float* eb1   = (const float*)d_in[5];
    const float* eW2   = (const float*)d_in[6];
    const float* eb2   = (const float*)d_in[7];
    const float* aW    = (const float*)d_in[8];
    const float* ab    = (const float*)d_in[9];
    const float* nW1   = (const float*)d_in[10];
    const float* nb1   = (const float*)d_in[11];
    const float* nW2   = (const float*)d_in[12];
    const float* nb2   = (const float*)d_in[13];
    const float* pW2   = (const float*)d_in[14];

    float* out    = (float*)d_out;
    float* hn_out = out;                                   // N*128
    float* po_out = out + (size_t)NN * 128;                // N*3
    float* m_out  = po_out + (size_t)NN * 3;               // E*128

    // ws layout (bytes)
    char* wsb = (char*)d_ws;
    float* agg        = (float*)(wsb + 0);                 // 25,600,000
    float* agg_t      = (float*)(wsb + 25600000);          //    600,000
    int*   deg        = (int*)  (wsb + 26200000);          //    200,000
    int*   row_ptr    = (int*)  (wsb + 26400000);          //    200,004
    int*   cursor     = (int*)  (wsb + 26600256);          //    200,000
    int*   edge_list  = (int*)  (wsb + 26800256);          //  2,560,000
    int*   row_sorted = (int*)  (wsb + 29360256);          //  2,560,000
    ushort_t* hbf     = (ushort_t*)(wsb + 31920256);       // 12,800,000

    // zero agg + agg_t + deg (contiguous)
    hipMemsetAsync(wsb, 0, 26400000, stream);

    prep_kernel<<<3200, 256, 0, stream>>>(h, hbf, eidx, deg);
    scan_kernel<<<1, 1024, 0, stream>>>(deg, row_ptr, cursor);
    scatter_kernel<<<(EE + 255) / 256, 256, 0, stream>>>(eidx, cursor, edge_list, row_sorted);

    egcl_edge_kernel<<<768, 256, 0, stream>>>(hbf, pos, eidx, eattr,
                                              edge_list, row_sorted,
                                              eW1, eb1, eW2, eb2, aW, ab, pW2,
                                              m_out, agg, agg_t);
    egcl_node_kernel<<<512, 256, 0, stream>>>(hbf, agg, agg_t, row_ptr, pos,
                                              nW1, nb1, nW2, nb2,
                                              hn_out, po_out);
}

// Round 12
// 519.012 us; speedup vs baseline: 1.1929x; 1.1337x over previous
//
#include <hip/hip_runtime.h>
#include <hip/hip_bf16.h>

#define NN 50000
#define EE 640000
#define FF 128
#define HH 128

typedef unsigned short ushort_t;
typedef unsigned int   uint_t;
using f32x4  = __attribute__((ext_vector_type(4))) float;
using bf16x8 = __attribute__((ext_vector_type(8))) __bf16;
using u16x8  = __attribute__((ext_vector_type(8))) unsigned short;

__device__ __forceinline__ ushort_t f2bf(float f) {
    union { float f; unsigned int i; } v; v.f = f;
    unsigned int r = v.i + 0x7fffu + ((v.i >> 16) & 1u);
    return (ushort_t)(r >> 16);
}
__device__ __forceinline__ float bf2f(uint_t u) {
    union { uint_t i; float f; } v; v.i = u << 16; return v.f;
}
__device__ __forceinline__ float fsilu(float x) { return x / (1.f + __expf(-x)); }
__device__ __forceinline__ float fsig(float x)  { return 1.f / (1.f + __expf(-x)); }

__device__ __forceinline__ u16x8 cvt8(const float* p) {
    float4 a0 = *reinterpret_cast<const float4*>(p);
    float4 a1 = *reinterpret_cast<const float4*>(p + 4);
    u16x8 v;
    v[0] = f2bf(a0.x); v[1] = f2bf(a0.y); v[2] = f2bf(a0.z); v[3] = f2bf(a0.w);
    v[4] = f2bf(a1.x); v[5] = f2bf(a1.y); v[6] = f2bf(a1.z); v[7] = f2bf(a1.w);
    return v;
}

// async global -> LDS, 16B per lane; dest = uniform base + lane*16
__device__ __forceinline__ void gld_lds16(const void* g, void* l) {
    typedef const __attribute__((address_space(1))) unsigned int glb_u32;
    typedef __attribute__((address_space(3))) unsigned int lds_u32;
    __builtin_amdgcn_global_load_lds((glb_u32*)g, (lds_u32*)l, 16, 0, 0);
}

// ---------------------------------------------------------------------------
// prep: h f32->bf16  +  degree histogram (fused)
// ---------------------------------------------------------------------------
__global__ void prep_kernel(const float* __restrict__ h, ushort_t* __restrict__ hbf,
                            const int* __restrict__ eidx, int* __restrict__ deg)
{
    const int t = blockIdx.x * 256 + threadIdx.x;
    if (t * 8 < NN * 128) {
        u16x8 v = cvt8(h + (size_t)t * 8);
        *reinterpret_cast<u16x8*>(hbf + (size_t)t * 8) = v;
    }
    if (t < EE) atomicAdd(&deg[eidx[t]], 1);
}

__global__ void scan_kernel(const int* __restrict__ deg, int* __restrict__ row_ptr,
                            int* __restrict__ cursor)
{
    __shared__ int sdata[1024];
    const int t = threadIdx.x;
    const int chunk = (NN + 1023) / 1024;
    const int start = t * chunk;
    const int end   = min(start + chunk, NN);
    int s = 0;
    for (int i = start; i < end; ++i) s += deg[i];
    sdata[t] = s;
    __syncthreads();
    for (int off = 1; off < 1024; off <<= 1) {
        int v = (t >= off) ? sdata[t - off] : 0;
        __syncthreads();
        sdata[t] += v;
        __syncthreads();
    }
    int ox = sdata[t] - s;
    for (int i = start; i < end; ++i) {
        row_ptr[i] = ox; cursor[i] = ox; ox += deg[i];
    }
    if (t == 1023) row_ptr[NN] = sdata[1023];
}

__global__ void scatter_kernel(const int* __restrict__ eidx, int* __restrict__ cursor,
                               int* __restrict__ edge_list, int* __restrict__ row_sorted)
{
    const int e = blockIdx.x * 256 + threadIdx.x;
    if (e < EE) {
        const int r = eidx[e];
        const int p = atomicAdd(&cursor[r], 1);
        edge_list[p] = e;
        row_sorted[p] = r;
    }
}

// ---------------------------------------------------------------------------
// Edge kernel, 256 threads, CSR-ordered 64-edge tiles, in-kernel aggregation.
// A_h[64][512B] staged via async global_load_lds (lane-linear dest, swizzled
// per-lane global src). A_misc[64][32B] holds dist/eattr. M2 aliases dead A_h.
// PD in staging-lane registers (+shfl). 5 barriers/tile. Grid 512 (2/CU, no
// tail). LDS 52,736 B.
// ---------------------------------------------------------------------------
#define M_STR 136   // ushorts (272 B)

__device__ __forceinline__ ushort_t* ah_ptr(ushort_t* base, int row, int b) {
    return base + row * 256 + ((b ^ ((row & 7) << 4)) >> 1);
}

__global__ __launch_bounds__(256, 2) void egcl_edge_kernel(
    const ushort_t* __restrict__ hbf, const float* __restrict__ pos,
    const int* __restrict__ eidx, const float* __restrict__ eattr,
    const int* __restrict__ edge_list, const int* __restrict__ row_sorted,
    const float* __restrict__ w1, const float* __restrict__ b1,
    const float* __restrict__ w2, const float* __restrict__ b2,
    const float* __restrict__ aW, const float* __restrict__ ab,
    const float* __restrict__ pW2,
    float* __restrict__ m_out, float* __restrict__ agg, float* __restrict__ agg_t)
{
    __shared__ __align__(16) ushort_t A_h[64 * 256];      // 32,768 B
    __shared__ __align__(16) ushort_t A_misc[64 * 16];    //  2,048 B
    __shared__ __align__(16) ushort_t M1_sh[64 * M_STR];  // 17,408 B
    __shared__ int   ROW_sh[64];
    __shared__ float GATE_sh[64];

    ushort_t* M2_sh = A_h;   // [64][M_STR], dead-A alias (17,408 <= 32,768)

    const int tid  = threadIdx.x;
    const int lane = tid & 63;
    const int w    = tid >> 6;
    const int l15  = lane & 15;
    const int lg   = lane >> 4;

    // ---- weights in registers (per wave: cols 32w..32w+31) ----
    bf16x8 B1[9][2];
    bf16x8 B2[4][2];
    bf16x8 Bg[4];
    float b1c[2], b2c[2];
    const float abv = ab[0];
#pragma unroll
    for (int nt = 0; nt < 2; ++nt) {
        const int colg = 32 * w + 16 * nt + l15;
        b1c[nt] = b1[colg];
        b2c[nt] = b2[colg];
#pragma unroll
        for (int ks = 0; ks < 9; ++ks) {
            u16x8 v;
#pragma unroll
            for (int j = 0; j < 8; ++j) {
                const int k = 32 * ks + 8 * lg + j;
                v[j] = (k < 265) ? f2bf(w1[k * 128 + colg]) : (ushort_t)0;
            }
            B1[ks][nt] = __builtin_bit_cast(bf16x8, v);
        }
#pragma unroll
        for (int ks = 0; ks < 4; ++ks) {
            u16x8 v;
#pragma unroll
            for (int j = 0; j < 8; ++j) {
                const int k = 32 * ks + 8 * lg + j;
                v[j] = f2bf(w2[k * 128 + colg]);
            }
            B2[ks][nt] = __builtin_bit_cast(bf16x8, v);
        }
    }
#pragma unroll
    for (int ks = 0; ks < 4; ++ks) {
        u16x8 v;
#pragma unroll
        for (int j = 0; j < 8; ++j) {
            const int k = 32 * ks + 8 * lg + j;
            v[j] = (l15 == 0) ? f2bf(aW[k]) : (l15 == 1 ? f2bf(pW2[k]) : (ushort_t)0);
        }
        Bg[ks] = __builtin_bit_cast(bf16x8, v);
    }

    const int ei = tid >> 2;   // CSR slot 0..63
    const int et = tid & 3;

    for (int tile = blockIdx.x; tile < EE / 64; tile += gridDim.x) {
        // ---- per-thread edge ids (4 threads/edge, redundant L1-hot loads) ----
        const int p  = tile * 64 + ei;
        const int eo = edge_list[p];
        const int r  = row_sorted[p];
        const int c  = eidx[EE + eo];

        // ---- async h staging: wave w fills A_h rows 16w..16w+15 ----
        // instr i writes 1KB: lanes 0..31 -> row 2i, lanes 32..63 -> row 2i+1
        // lane byte-in-row bs=(lane&31)*16; logical b = bs ^ ((row&7)<<4);
        // b<256 -> h[row-node], else h[col-node].
#pragma unroll
        for (int i = 0; i < 8; ++i) {
            const int rl = 2 * i + (lane >> 5);           // row_local 0..15
            const int bs = (lane & 31) << 4;
            const int b  = bs ^ ((rl & 7) << 4);          // row&7 == rl&7
            const int rr = __shfl(r, 4 * rl);
            const int cc = __shfl(c, 4 * rl);
            const int node = (b < 256) ? rr : cc;
            const char* src = (const char*)hbf + (size_t)node * 256 + (b & 255);
            gld_lds16(src, (char*)A_h + (w * 8192 + i * 1024));
        }

        // ---- misc staging (dist^2 + eattr) + ROW + pd regs ----
        float pdx = 0.f, pdy = 0.f, pdz = 0.f;
        if (et == 0) {
            ROW_sh[ei] = r;
            pdx = pos[r * 3 + 0] - pos[c * 3 + 0];
            pdy = pos[r * 3 + 1] - pos[c * 3 + 1];
            pdz = pos[r * 3 + 2] - pos[c * 3 + 2];
            const float ds = pdx * pdx + pdy * pdy + pdz * pdz;
            const float4 ea0 = *reinterpret_cast<const float4*>(eattr + (size_t)eo * 8);
            const float4 ea1 = *reinterpret_cast<const float4*>(eattr + (size_t)eo * 8 + 4);
            u16x8 v0;
            v0[0] = f2bf(ds);
            v0[1] = f2bf(ea0.x); v0[2] = f2bf(ea0.y); v0[3] = f2bf(ea0.z);
            v0[4] = f2bf(ea0.w); v0[5] = f2bf(ea1.x); v0[6] = f2bf(ea1.y);
            v0[7] = f2bf(ea1.z);
            *reinterpret_cast<u16x8*>(&A_misc[ei * 16]) = v0;
            u16x8 v1 = {0, 0, 0, 0, 0, 0, 0, 0};
            v1[0] = f2bf(ea1.w);
            *reinterpret_cast<u16x8*>(&A_misc[ei * 16 + 8]) = v1;
        }
        __syncthreads();                       // B1: A_h (vmcnt drain) + misc + ROW

        // ---- layer 1 ----
#pragma unroll
        for (int s = 0; s < 4; ++s) {
            f32x4 a0 = {0.f, 0.f, 0.f, 0.f};
            f32x4 a1 = {0.f, 0.f, 0.f, 0.f};
#pragma unroll
            for (int ks = 0; ks < 9; ++ks) {
                bf16x8 a;
                if (ks < 8) {
                    a = *reinterpret_cast<const bf16x8*>(
                        ah_ptr(A_h, 16 * s + l15, 64 * ks + 16 * lg));
                } else if (lg < 2) {
                    a = *reinterpret_cast<const bf16x8*>(
                        &A_misc[(16 * s + l15) * 16 + 8 * lg]);
                } else {
                    u16x8 z = {0, 0, 0, 0, 0, 0, 0, 0};
                    a = __builtin_bit_cast(bf16x8, z);   // k>=272: B1 zero there too
                }
                a0 = __builtin_amdgcn_mfma_f32_16x16x32_bf16(a, B1[ks][0], a0, 0, 0, 0);
                a1 = __builtin_amdgcn_mfma_f32_16x16x32_bf16(a, B1[ks][1], a1, 0, 0, 0);
            }
#pragma unroll
            for (int nt = 0; nt < 2; ++nt) {
#pragma unroll
                for (int rr2 = 0; rr2 < 4; ++rr2) {
                    const float x = (nt == 0 ? a0[rr2] : a1[rr2]) + b1c[nt];
                    const int edge = 16 * s + 4 * lg + rr2;
                    const int colg = 32 * w + 16 * nt + l15;
                    M1_sh[edge * M_STR + colg] = f2bf(fsilu(x));
                }
            }
        }
        __syncthreads();                       // B2: M1 ready, A_h dead

        // ---- layer 2 -> M2 (bf16, dead-A alias) ----
#pragma unroll
        for (int s = 0; s < 4; ++s) {
            f32x4 a0 = {0.f, 0.f, 0.f, 0.f};
            f32x4 a1 = {0.f, 0.f, 0.f, 0.f};
#pragma unroll
            for (int ks = 0; ks < 4; ++ks) {
                bf16x8 a = *reinterpret_cast<const bf16x8*>(
                    &M1_sh[(16 * s + l15) * M_STR + ks * 32 + lg * 8]);
                a0 = __builtin_amdgcn_mfma_f32_16x16x32_bf16(a, B2[ks][0], a0, 0, 0, 0);
                a1 = __builtin_amdgcn_mfma_f32_16x16x32_bf16(a, B2[ks][1], a1, 0, 0, 0);
            }
#pragma unroll
            for (int nt = 0; nt < 2; ++nt) {
#pragma unroll
                for (int rr2 = 0; rr2 < 4; ++rr2) {
                    const float x = (nt == 0 ? a0[rr2] : a1[rr2]) + b2c[nt];
                    const int edge = 16 * s + 4 * lg + rr2;
                    const int colg = 32 * w + 16 * nt + l15;
                    M2_sh[edge * M_STR + colg] = f2bf(fsilu(x));
                }
            }
        }
        __syncthreads();                       // B3: M2 ready

        // ---- gate: own subtile (4 MFMA) -> GATE_sh + trans flush ----
        {
            f32x4 ga = {0.f, 0.f, 0.f, 0.f};
#pragma unroll
            for (int ks = 0; ks < 4; ++ks) {
                bf16x8 a = *reinterpret_cast<const bf16x8*>(
                    &M2_sh[(16 * w + l15) * M_STR + ks * 32 + lg * 8]);
                ga = __builtin_amdgcn_mfma_f32_16x16x32_bf16(a, Bg[ks], ga, 0, 0, 0);
            }
            float gqw[4], txw[4], tyw[4], tzw[4];
#pragma unroll
            for (int rr2 = 0; rr2 < 4; ++rr2) {
                const float sa = __shfl(ga[rr2], lane & 48);
                const float sp = __shfl(ga[rr2], (lane & 48) + 1);
                gqw[rr2] = fsig(sa + abv);
                const float t = gqw[rr2] * sp;
                const float px = __shfl(pdx, 16 * lg + 4 * rr2);
                const float py = __shfl(pdy, 16 * lg + 4 * rr2);
                const float pz = __shfl(pdz, 16 * lg + 4 * rr2);
                txw[rr2] = px * t; tyw[rr2] = py * t; tzw[rr2] = pz * t;
                if (l15 == 0) GATE_sh[16 * w + 4 * lg + rr2] = gqw[rr2];
            }
            if (l15 == 0) {
                int cur = -1; float t0 = 0.f, t1 = 0.f, t2 = 0.f;
#pragma unroll
                for (int rr2 = 0; rr2 < 4; ++rr2) {
                    const int rid = ROW_sh[16 * w + 4 * lg + rr2];
                    if (rid != cur) {
                        if (cur >= 0) {
                            atomicAdd(&agg_t[cur * 3 + 0], t0);
                            atomicAdd(&agg_t[cur * 3 + 1], t1);
                            atomicAdd(&agg_t[cur * 3 + 2], t2);
                        }
                        cur = rid; t0 = t1 = t2 = 0.f;
                    }
                    t0 += txw[rr2]; t1 += tyw[rr2]; t2 += tzw[rr2];
                }
                atomicAdd(&agg_t[cur * 3 + 0], t0);
                atomicAdd(&agg_t[cur * 3 + 1], t1);
                atomicAdd(&agg_t[cur * 3 + 2], t2);
            }
        }
        __syncthreads();                       // B4: GATE_sh visible

        // ---- coalesced gated m_out: wave w owns rows 16w..16w+15 ----
#pragma unroll
        for (int j = 0; j < 16; ++j) {
            const int row = 16 * w + j;
            const int eo2 = edge_list[tile * 64 + row];
            const uint_t pv = *reinterpret_cast<const uint_t*>(&M2_sh[row * M_STR + 2 * lane]);
            const float g = GATE_sh[row];
            float2 st;
            st.x = bf2f(pv & 0xffffu) * g;
            st.y = bf2f(pv >> 16) * g;
            *reinterpret_cast<float2*>(&m_out[(size_t)eo2 * 128 + 2 * lane]) = st;
        }

        // ---- segmented column scan: agg[row] += gated m sums ----
        {
            const int col = tid & 127;
            const int j0  = (tid >> 7) * 32;
            int cur = ROW_sh[j0];
            float acc = 0.f;
#pragma unroll 4
            for (int j = j0; j < j0 + 32; ++j) {
                const int rid = ROW_sh[j];
                const float v = bf2f((uint_t)M2_sh[j * M_STR + col]) * GATE_sh[j];
                if (rid != cur) {
                    atomicAdd(&agg[(size_t)cur * 128 + col], acc);
                    acc = 0.f; cur = rid;
                }
                acc += v;
            }
            atomicAdd(&agg[(size_t)cur * 128 + col], acc);
        }
        __syncthreads();                       // B5: protect LDS for next tile
    }
}

// ---------------------------------------------------------------------------
// Node kernel: streaming. h_new = silu([hbf|bf16(agg)]@nW1+nb1)@nW2+nb2+h,
// residual from LDS (bf16). pos_new = pos + agg_t / max(deg,1).
// ---------------------------------------------------------------------------
__global__ __launch_bounds__(256, 4) void egcl_node_kernel(
    const ushort_t* __restrict__ hbf,
    const float* __restrict__ agg, const float* __restrict__ agg_t,
    const int* __restrict__ row_ptr, const float* __restrict__ pos,
    const float* __restrict__ w1, const float* __restrict__ b1,
    const float* __restrict__ w2, const float* __restrict__ b2,
    float* __restrict__ hn_out, float* __restrict__ pos_out)
{
    __shared__ __align__(16) ushort_t A_sh[16 * 264];
    __shared__ __align__(16) ushort_t M1_sh[16 * 136];

    const int tid  = threadIdx.x;
    const int lane = tid & 63;
    const int w    = tid >> 6;
    const int l15  = lane & 15;
    const int lg   = lane >> 4;

    bf16x8 B1[8][2];
    bf16x8 B2[4][2];
    float b1c[2], b2c[2];
#pragma unroll
    for (int nt = 0; nt < 2; ++nt) {
        const int colg = 32 * w + 16 * nt + l15;
        b1c[nt] = b1[colg];
        b2c[nt] = b2[colg];
#pragma unroll
        for (int ks = 0; ks < 8; ++ks) {
            u16x8 v;
#pragma unroll
            for (int j = 0; j < 8; ++j) {
                const int k = 32 * ks + 8 * lg + j;
                v[j] = f2bf(w1[k * 128 + colg]);
            }
            B1[ks][nt] = __builtin_bit_cast(bf16x8, v);
        }
#pragma unroll
        for (int ks = 0; ks < 4; ++ks) {
            u16x8 v;
#pragma unroll
            for (int j = 0; j < 8; ++j) {
                const int k = 32 * ks + 8 * lg + j;
                v[j] = f2bf(w2[k * 128 + colg]);
            }
            B2[ks][nt] = __builtin_bit_cast(bf16x8, v);
        }
    }

    const int ni = tid >> 4;
    const int nt16 = tid & 15;

    for (int tile = blockIdx.x; tile < NN / 16; tile += gridDim.x) {
        __syncthreads();
        const int base = tile * 16;
        {
            const size_t n = (size_t)base + ni;
            *reinterpret_cast<u16x8*>(&A_sh[ni * 264 + nt16 * 8]) =
                *reinterpret_cast<const u16x8*>(hbf + n * 128 + nt16 * 8);
            u16x8 av = cvt8(agg + n * 128 + nt16 * 8);
            *reinterpret_cast<u16x8*>(&A_sh[ni * 264 + 128 + nt16 * 8]) = av;
        }
        if (tid < 48) {
            const int nl = tid / 3, d = tid % 3;
            const size_t n = (size_t)base + nl;
            const float c = (float)(row_ptr[n + 1] - row_ptr[n]);
            pos_out[n * 3 + d] = pos[n * 3 + d] + agg_t[n * 3 + d] / fmaxf(c, 1.f);
        }
        __syncthreads();

        f32x4 acc10 = {0.f, 0.f, 0.f, 0.f};
        f32x4 acc11 = {0.f, 0.f, 0.f, 0.f};
#pragma unroll
        for (int ks = 0; ks < 8; ++ks) {
            bf16x8 a = *reinterpret_cast<const bf16x8*>(&A_sh[l15 * 264 + ks * 32 + lg * 8]);
            acc10 = __builtin_amdgcn_mfma_f32_16x16x32_bf16(a, B1[ks][0], acc10, 0, 0, 0);
            acc11 = __builtin_amdgcn_mfma_f32_16x16x32_bf16(a, B1[ks][1], acc11, 0, 0, 0);
        }
#pragma unroll
        for (int nt = 0; nt < 2; ++nt) {
#pragma unroll
            for (int r = 0; r < 4; ++r) {
                const float x = (nt == 0 ? acc10[r] : acc11[r]) + b1c[nt];
                const int nl = 4 * lg + r;
                const int colg = 32 * w + 16 * nt + l15;
                M1_sh[nl * 136 + colg] = f2bf(fsilu(x));
            }
        }
        __syncthreads();

        f32x4 acc20 = {0.f, 0.f, 0.f, 0.f};
        f32x4 acc21 = {0.f, 0.f, 0.f, 0.f};
#pragma unroll
        for (int ks = 0; ks < 4; ++ks) {
            bf16x8 a = *reinterpret_cast<const bf16x8*>(&M1_sh[l15 * 136 + ks * 32 + lg * 8]);
            acc20 = __builtin_amdgcn_mfma_f32_16x16x32_bf16(a, B2[ks][0], acc20, 0, 0, 0);
            acc21 = __builtin_amdgcn_mfma_f32_16x16x32_bf16(a, B2[ks][1], acc21, 0, 0, 0);
        }
#pragma unroll
        for (int nt = 0; nt < 2; ++nt) {
#pragma unroll
            for (int r = 0; r < 4; ++r) {
                const int nl = 4 * lg + r;
                const int colg = 32 * w + 16 * nt + l15;
                const size_t n = (size_t)base + nl;
                const float hres = bf2f((uint_t)A_sh[nl * 264 + colg]);
                const float y = (nt == 0 ? acc20[r] : acc21[r]) + b2c[nt] + hres;
                hn_out[n * 128 + colg] = y;
            }
        }
    }
}

extern "C" void kernel_launch(void* const* d_in, const int* in_sizes, int n_in,
                              void* d_out, int out_size, void* d_ws, size_t ws_size,
                              hipStream_t stream)
{
    const float* h     = (const float*)d_in[0];
    const float* pos   = (const float*)d_in[1];
    const int*   eidx  = (const int*)d_in[2];
    const float* eattr = (const float*)d_in[3];
    const float* eW1   = (const float*)d_in[4];
    const float* eb1   = (const float*)d_in[5];
    const float* eW2   = (const float*)d_in[6];
    const float* eb2   = (const float*)d_in[7];
    const float* aW    = (const float*)d_in[8];
    const float* ab    = (const float*)d_in[9];
    const float* nW1   = (const float*)d_in[10];
    const float* nb1   = (const float*)d_in[11];
    const float* nW2   = (const float*)d_in[12];
    const float* nb2   = (const float*)d_in[13];
    const float* pW2   = (const float*)d_in[14];

    float* out    = (float*)d_out;
    float* hn_out = out;                                   // N*128
    float* po_out = out + (size_t)NN * 128;                // N*3
    float* m_out  = po_out + (size_t)NN * 3;               // E*128

    // ws layout (bytes)
    char* wsb = (char*)d_ws;
    float* agg        = (float*)(wsb + 0);                 // 25,600,000
    float* agg_t      = (float*)(wsb + 25600000);          //    600,000
    int*   deg        = (int*)  (wsb + 26200000);          //    200,000
    int*   row_ptr    = (int*)  (wsb + 26400000);          //    200,004
    int*   cursor     = (int*)  (wsb + 26600256);          //    200,000
    int*   edge_list  = (int*)  (wsb + 26800256);          //  2,560,000
    int*   row_sorted = (int*)  (wsb + 29360256);          //  2,560,000
    ushort_t* hbf     = (ushort_t*)(wsb + 31920256);       // 12,800,000

    // zero agg + agg_t + deg (contiguous)
    hipMemsetAsync(wsb, 0, 26400000, stream);

    prep_kernel<<<3200, 256, 0, stream>>>(h, hbf, eidx, deg);
    scan_kernel<<<1, 1024, 0, stream>>>(deg, row_ptr, cursor);
    scatter_kernel<<<(EE + 255) / 256, 256, 0, stream>>>(eidx, cursor, edge_list, row_sorted);

    egcl_edge_kernel<<<512, 256, 0, stream>>>(hbf, pos, eidx, eattr,
                                              edge_list, row_sorted,
                                              eW1, eb1, eW2, eb2, aW, ab, pW2,
                                              m_out, agg, agg_t);
    egcl_node_kernel<<<512, 256, 0, stream>>>(hbf, agg, agg_t, row_ptr, pos,
                                              nW1, nb1, nW2, nb2,
                                              hn_out, po_out);
}

// Round 13
// 431.261 us; speedup vs baseline: 1.4356x; 1.2035x over previous
//
#include <hip/hip_runtime.h>
#include <hip/hip_bf16.h>

#define NN 50000
#define EE 640000
#define FF 128
#define HH 128

typedef unsigned short ushort_t;
typedef unsigned int   uint_t;
using f32x4  = __attribute__((ext_vector_type(4))) float;
using bf16x8 = __attribute__((ext_vector_type(8))) __bf16;
using u16x8  = __attribute__((ext_vector_type(8))) unsigned short;

__device__ __forceinline__ ushort_t f2bf(float f) {
    union { float f; unsigned int i; } v; v.f = f;
    unsigned int r = v.i + 0x7fffu + ((v.i >> 16) & 1u);
    return (ushort_t)(r >> 16);
}
__device__ __forceinline__ float bf2f(uint_t u) {
    union { uint_t i; float f; } v; v.i = u << 16; return v.f;
}
__device__ __forceinline__ float fsilu(float x) { return x / (1.f + __expf(-x)); }
__device__ __forceinline__ float fsig(float x)  { return 1.f / (1.f + __expf(-x)); }

__device__ __forceinline__ u16x8 cvt8(const float* p) {
    float4 a0 = *reinterpret_cast<const float4*>(p);
    float4 a1 = *reinterpret_cast<const float4*>(p + 4);
    u16x8 v;
    v[0] = f2bf(a0.x); v[1] = f2bf(a0.y); v[2] = f2bf(a0.z); v[3] = f2bf(a0.w);
    v[4] = f2bf(a1.x); v[5] = f2bf(a1.y); v[6] = f2bf(a1.z); v[7] = f2bf(a1.w);
    return v;
}

// async global -> LDS, 16B per lane; dest = uniform base + lane*16
__device__ __forceinline__ void gld_lds16(const void* g, void* l) {
    typedef const __attribute__((address_space(1))) unsigned int glb_u32;
    typedef __attribute__((address_space(3))) unsigned int lds_u32;
    __builtin_amdgcn_global_load_lds((glb_u32*)g, (lds_u32*)l, 16, 0, 0);
}

// ---------------------------------------------------------------------------
// prep: h f32->bf16 + degree histogram + agg zeroing (all fused)
// ---------------------------------------------------------------------------
__global__ void prep_kernel(const float* __restrict__ h, ushort_t* __restrict__ hbf,
                            const int* __restrict__ eidx, int* __restrict__ deg,
                            float* __restrict__ agg)
{
    const int t = blockIdx.x * 256 + threadIdx.x;
    if (t < 800000) {
        u16x8 v = cvt8(h + (size_t)t * 8);
        *reinterpret_cast<u16x8*>(hbf + (size_t)t * 8) = v;
        const float4 z4 = {0.f, 0.f, 0.f, 0.f};
        *reinterpret_cast<float4*>(agg + (size_t)t * 8)     = z4;
        *reinterpret_cast<float4*>(agg + (size_t)t * 8 + 4) = z4;
    }
    if (t < EE) atomicAdd(&deg[eidx[t]], 1);
}

// ---------------------------------------------------------------------------
// 3-kernel coalesced scan: local block scan -> block-sum scan -> fix-up
// ---------------------------------------------------------------------------
__global__ void scan_local_kernel(const int* __restrict__ deg,
                                  int* __restrict__ row_ptr, int* __restrict__ bsum)
{
    __shared__ int sd[256];
    const int t = threadIdx.x;
    const int i = blockIdx.x * 256 + t;
    const int v = (i < NN) ? deg[i] : 0;
    sd[t] = v;
    __syncthreads();
    for (int off = 1; off < 256; off <<= 1) {
        const int u = (t >= off) ? sd[t - off] : 0;
        __syncthreads();
        sd[t] += u;
        __syncthreads();
    }
    if (i < NN) row_ptr[i] = sd[t] - v;          // exclusive-in-block
    if (t == 255) bsum[blockIdx.x] = sd[255];
}

__global__ void scan_bsum_kernel(int* __restrict__ bsum)
{
    __shared__ int sd[256];
    const int t = threadIdx.x;
    const int v = (t < 196) ? bsum[t] : 0;
    sd[t] = v;
    __syncthreads();
    for (int off = 1; off < 256; off <<= 1) {
        const int u = (t >= off) ? sd[t - off] : 0;
        __syncthreads();
        sd[t] += u;
        __syncthreads();
    }
    if (t < 196) bsum[t] = sd[t] - v;            // exclusive
}

__global__ void scan_fix_kernel(int* __restrict__ row_ptr, const int* __restrict__ bsum,
                                int* __restrict__ cursor)
{
    const int i = blockIdx.x * 256 + threadIdx.x;
    if (i < NN) {
        const int p = row_ptr[i] + bsum[blockIdx.x];
        row_ptr[i] = p;
        cursor[i]  = p;
    }
    if (i == 0) row_ptr[NN] = EE;
}

__global__ void scatter_kernel(const int* __restrict__ eidx, int* __restrict__ cursor,
                               int* __restrict__ edge_list, int* __restrict__ row_sorted)
{
    const int e = blockIdx.x * 256 + threadIdx.x;
    if (e < EE) {
        const int r = eidx[e];
        const int p = atomicAdd(&cursor[r], 1);
        edge_list[p] = e;
        row_sorted[p] = r;
    }
}

// ---------------------------------------------------------------------------
// Edge kernel, 256 threads, CSR-ordered 64-edge tiles, 3 barriers/tile.
// A_h[64][512B] via async DMA (wave w owns its 8KB block). M2 aliases A_h in
// WAVE-BLOCK layout: m2_off(row) = (row>>4)*4096 + (row&15)*136 ushorts, so
// post-B3 phases (gate, fused m_out+agg, next-tile staging) are wave-local.
// ---------------------------------------------------------------------------
#define M_STR 136   // ushorts (272 B)

__device__ __forceinline__ ushort_t* ah_ptr(ushort_t* base, int row, int b) {
    return base + row * 256 + ((b ^ ((row & 7) << 4)) >> 1);
}
__device__ __forceinline__ int m2_off(int row) {
    return (row >> 4) * 4096 + (row & 15) * M_STR;   // ushort offset
}

__global__ __launch_bounds__(256, 2) void egcl_edge_kernel(
    const ushort_t* __restrict__ hbf, const float* __restrict__ pos,
    const int* __restrict__ eidx, const float* __restrict__ eattr,
    const int* __restrict__ edge_list, const int* __restrict__ row_sorted,
    const float* __restrict__ w1, const float* __restrict__ b1,
    const float* __restrict__ w2, const float* __restrict__ b2,
    const float* __restrict__ aW, const float* __restrict__ ab,
    const float* __restrict__ pW2,
    float* __restrict__ m_out, float* __restrict__ agg, float* __restrict__ agg_t)
{
    __shared__ __align__(16) ushort_t A_h[64 * 256];      // 32,768 B
    __shared__ __align__(16) ushort_t A_misc[64 * 16];    //  2,048 B
    __shared__ __align__(16) ushort_t M1_sh[64 * M_STR];  // 17,408 B
    __shared__ int   ROW_sh[64];
    __shared__ float GATE_sh[64];

    ushort_t* M2_sh = A_h;   // wave-block alias

    const int tid  = threadIdx.x;
    const int lane = tid & 63;
    const int w    = tid >> 6;
    const int l15  = lane & 15;
    const int lg   = lane >> 4;

    // ---- weights in registers (per wave: cols 32w..32w+31) ----
    bf16x8 B1[9][2];
    bf16x8 B2[4][2];
    bf16x8 Bg[4];
    float b1c[2], b2c[2];
    const float abv = ab[0];
#pragma unroll
    for (int nt = 0; nt < 2; ++nt) {
        const int colg = 32 * w + 16 * nt + l15;
        b1c[nt] = b1[colg];
        b2c[nt] = b2[colg];
#pragma unroll
        for (int ks = 0; ks < 9; ++ks) {
            u16x8 v;
#pragma unroll
            for (int j = 0; j < 8; ++j) {
                const int k = 32 * ks + 8 * lg + j;
                v[j] = (k < 265) ? f2bf(w1[k * 128 + colg]) : (ushort_t)0;
            }
            B1[ks][nt] = __builtin_bit_cast(bf16x8, v);
        }
#pragma unroll
        for (int ks = 0; ks < 4; ++ks) {
            u16x8 v;
#pragma unroll
            for (int j = 0; j < 8; ++j) {
                const int k = 32 * ks + 8 * lg + j;
                v[j] = f2bf(w2[k * 128 + colg]);
            }
            B2[ks][nt] = __builtin_bit_cast(bf16x8, v);
        }
    }
#pragma unroll
    for (int ks = 0; ks < 4; ++ks) {
        u16x8 v;
#pragma unroll
        for (int j = 0; j < 8; ++j) {
            const int k = 32 * ks + 8 * lg + j;
            v[j] = (l15 == 0) ? f2bf(aW[k]) : (l15 == 1 ? f2bf(pW2[k]) : (ushort_t)0);
        }
        Bg[ks] = __builtin_bit_cast(bf16x8, v);
    }

    const int ei = tid >> 2;   // CSR slot 0..63
    const int et = tid & 3;
    const int NT = EE / 64;

    float pdx = 0.f, pdy = 0.f, pdz = 0.f;

    // stage tile t: DMA h rows into own A_h block + misc + ROW + pd regs
    auto do_stage = [&](int t) {
        const int p  = t * 64 + ei;
        const int eo = edge_list[p];
        const int r  = row_sorted[p];
        const int c  = eidx[EE + eo];
#pragma unroll
        for (int i = 0; i < 8; ++i) {
            const int rl = 2 * i + (lane >> 5);           // row_local 0..15
            const int bs = (lane & 31) << 4;
            const int b  = bs ^ ((rl & 7) << 4);
            const int rr = __shfl(r, 4 * rl);
            const int cc = __shfl(c, 4 * rl);
            const int node = (b < 256) ? rr : cc;
            const char* src = (const char*)hbf + (size_t)node * 256 + (b & 255);
            gld_lds16(src, (char*)A_h + (w * 8192 + i * 1024));
        }
        if (et == 0) {
            ROW_sh[ei] = r;
            pdx = pos[r * 3 + 0] - pos[c * 3 + 0];
            pdy = pos[r * 3 + 1] - pos[c * 3 + 1];
            pdz = pos[r * 3 + 2] - pos[c * 3 + 2];
            const float ds = pdx * pdx + pdy * pdy + pdz * pdz;
            const float4 ea0 = *reinterpret_cast<const float4*>(eattr + (size_t)eo * 8);
            const float4 ea1 = *reinterpret_cast<const float4*>(eattr + (size_t)eo * 8 + 4);
            u16x8 v0;
            v0[0] = f2bf(ds);
            v0[1] = f2bf(ea0.x); v0[2] = f2bf(ea0.y); v0[3] = f2bf(ea0.z);
            v0[4] = f2bf(ea0.w); v0[5] = f2bf(ea1.x); v0[6] = f2bf(ea1.y);
            v0[7] = f2bf(ea1.z);
            *reinterpret_cast<u16x8*>(&A_misc[ei * 16]) = v0;
            u16x8 v1 = {0, 0, 0, 0, 0, 0, 0, 0};
            v1[0] = f2bf(ea1.w);
            *reinterpret_cast<u16x8*>(&A_misc[ei * 16 + 8]) = v1;
        }
    };

    do_stage(blockIdx.x);   // prologue

    for (int tile = blockIdx.x; tile < NT; tile += gridDim.x) {
        __syncthreads();                       // B1: DMA drained + misc/ROW visible

        // ---- layer 1 ----
#pragma unroll
        for (int s = 0; s < 4; ++s) {
            f32x4 a0 = {0.f, 0.f, 0.f, 0.f};
            f32x4 a1 = {0.f, 0.f, 0.f, 0.f};
#pragma unroll
            for (int ks = 0; ks < 9; ++ks) {
                bf16x8 a;
                if (ks < 8) {
                    a = *reinterpret_cast<const bf16x8*>(
                        ah_ptr(A_h, 16 * s + l15, 64 * ks + 16 * lg));
                } else if (lg < 2) {
                    a = *reinterpret_cast<const bf16x8*>(
                        &A_misc[(16 * s + l15) * 16 + 8 * lg]);
                } else {
                    u16x8 z = {0, 0, 0, 0, 0, 0, 0, 0};
                    a = __builtin_bit_cast(bf16x8, z);
                }
                a0 = __builtin_amdgcn_mfma_f32_16x16x32_bf16(a, B1[ks][0], a0, 0, 0, 0);
                a1 = __builtin_amdgcn_mfma_f32_16x16x32_bf16(a, B1[ks][1], a1, 0, 0, 0);
            }
#pragma unroll
            for (int nt = 0; nt < 2; ++nt) {
#pragma unroll
                for (int rr2 = 0; rr2 < 4; ++rr2) {
                    const float x = (nt == 0 ? a0[rr2] : a1[rr2]) + b1c[nt];
                    const int edge = 16 * s + 4 * lg + rr2;
                    const int colg = 32 * w + 16 * nt + l15;
                    M1_sh[edge * M_STR + colg] = f2bf(fsilu(x));
                }
            }
        }
        __syncthreads();                       // B2: M1 ready, A_h dead

        // ---- layer 2 -> M2 (wave-block alias layout) ----
#pragma unroll
        for (int s = 0; s < 4; ++s) {
            f32x4 a0 = {0.f, 0.f, 0.f, 0.f};
            f32x4 a1 = {0.f, 0.f, 0.f, 0.f};
#pragma unroll
            for (int ks = 0; ks < 4; ++ks) {
                bf16x8 a = *reinterpret_cast<const bf16x8*>(
                    &M1_sh[(16 * s + l15) * M_STR + ks * 32 + lg * 8]);
                a0 = __builtin_amdgcn_mfma_f32_16x16x32_bf16(a, B2[ks][0], a0, 0, 0, 0);
                a1 = __builtin_amdgcn_mfma_f32_16x16x32_bf16(a, B2[ks][1], a1, 0, 0, 0);
            }
#pragma unroll
            for (int nt = 0; nt < 2; ++nt) {
#pragma unroll
                for (int rr2 = 0; rr2 < 4; ++rr2) {
                    const float x = (nt == 0 ? a0[rr2] : a1[rr2]) + b2c[nt];
                    const int edge = 16 * s + 4 * lg + rr2;
                    const int colg = 32 * w + 16 * nt + l15;
                    M2_sh[m2_off(edge) + colg] = f2bf(fsilu(x));
                }
            }
        }
        __syncthreads();                       // B3: M2 ready (last barrier of tile)

        // ---- gate: own rows (4 MFMA) -> GATE_sh + agg_t flush (wave-local) ----
        {
            f32x4 ga = {0.f, 0.f, 0.f, 0.f};
#pragma unroll
            for (int ks = 0; ks < 4; ++ks) {
                bf16x8 a = *reinterpret_cast<const bf16x8*>(
                    &M2_sh[m2_off(16 * w + l15) + ks * 32 + lg * 8]);
                ga = __builtin_amdgcn_mfma_f32_16x16x32_bf16(a, Bg[ks], ga, 0, 0, 0);
            }
            float gqw[4], txw[4], tyw[4], tzw[4];
#pragma unroll
            for (int rr2 = 0; rr2 < 4; ++rr2) {
                const float sa = __shfl(ga[rr2], lane & 48);
                const float sp = __shfl(ga[rr2], (lane & 48) + 1);
                gqw[rr2] = fsig(sa + abv);
                const float t = gqw[rr2] * sp;
                const float px = __shfl(pdx, 16 * lg + 4 * rr2);
                const float py = __shfl(pdy, 16 * lg + 4 * rr2);
                const float pz = __shfl(pdz, 16 * lg + 4 * rr2);
                txw[rr2] = px * t; tyw[rr2] = py * t; tzw[rr2] = pz * t;
                if (l15 == 0) GATE_sh[16 * w + 4 * lg + rr2] = gqw[rr2];
            }
            if (l15 == 0) {
                int cur = -1; float t0 = 0.f, t1 = 0.f, t2 = 0.f;
#pragma unroll
                for (int rr2 = 0; rr2 < 4; ++rr2) {
                    const int rid = ROW_sh[16 * w + 4 * lg + rr2];
                    if (rid != cur) {
                        if (cur >= 0) {
                            atomicAdd(&agg_t[cur * 3 + 0], t0);
                            atomicAdd(&agg_t[cur * 3 + 1], t1);
                            atomicAdd(&agg_t[cur * 3 + 2], t2);
                        }
                        cur = rid; t0 = t1 = t2 = 0.f;
                    }
                    t0 += txw[rr2]; t1 += tyw[rr2]; t2 += tzw[rr2];
                }
                atomicAdd(&agg_t[cur * 3 + 0], t0);
                atomicAdd(&agg_t[cur * 3 + 1], t1);
                atomicAdd(&agg_t[cur * 3 + 2], t2);
            }
        }

        // ---- fused m_out write + agg accumulation (own rows, no barrier) ----
        {
            float ax = 0.f, ay = 0.f;
            int cur = ROW_sh[16 * w];
#pragma unroll
            for (int j = 0; j < 16; ++j) {
                const int row = 16 * w + j;
                const int rid = ROW_sh[row];
                const int eo2 = edge_list[tile * 64 + row];
                const uint_t pv = *reinterpret_cast<const uint_t*>(
                    &M2_sh[m2_off(row) + 2 * lane]);
                const float g = GATE_sh[row];
                float2 st;
                st.x = bf2f(pv & 0xffffu) * g;
                st.y = bf2f(pv >> 16) * g;
                *reinterpret_cast<float2*>(&m_out[(size_t)eo2 * 128 + 2 * lane]) = st;
                if (rid != cur) {
                    atomicAdd(&agg[(size_t)cur * 128 + 2 * lane],     ax);
                    atomicAdd(&agg[(size_t)cur * 128 + 2 * lane + 1], ay);
                    cur = rid; ax = 0.f; ay = 0.f;
                }
                ax += st.x; ay += st.y;
            }
            atomicAdd(&agg[(size_t)cur * 128 + 2 * lane],     ax);
            atomicAdd(&agg[(size_t)cur * 128 + 2 * lane + 1], ay);
        }

        // ---- pipeline: stage next tile into own A_h block (wave-local) ----
        asm volatile("s_waitcnt lgkmcnt(0)" ::: "memory");
        __builtin_amdgcn_sched_barrier(0);
        const int nxt = tile + gridDim.x;
        if (nxt < NT) do_stage(nxt);
    }
}

// ---------------------------------------------------------------------------
// Node kernel: streaming. h_new = silu([hbf|bf16(agg)]@nW1+nb1)@nW2+nb2+h,
// residual from LDS (bf16). pos_new = pos + agg_t / max(deg,1).
// ---------------------------------------------------------------------------
__global__ __launch_bounds__(256, 4) void egcl_node_kernel(
    const ushort_t* __restrict__ hbf,
    const float* __restrict__ agg, const float* __restrict__ agg_t,
    const int* __restrict__ row_ptr, const float* __restrict__ pos,
    const float* __restrict__ w1, const float* __restrict__ b1,
    const float* __restrict__ w2, const float* __restrict__ b2,
    float* __restrict__ hn_out, float* __restrict__ pos_out)
{
    __shared__ __align__(16) ushort_t A_sh[16 * 264];
    __shared__ __align__(16) ushort_t M1_sh[16 * 136];

    const int tid  = threadIdx.x;
    const int lane = tid & 63;
    const int w    = tid >> 6;
    const int l15  = lane & 15;
    const int lg   = lane >> 4;

    bf16x8 B1[8][2];
    bf16x8 B2[4][2];
    float b1c[2], b2c[2];
#pragma unroll
    for (int nt = 0; nt < 2; ++nt) {
        const int colg = 32 * w + 16 * nt + l15;
        b1c[nt] = b1[colg];
        b2c[nt] = b2[colg];
#pragma unroll
        for (int ks = 0; ks < 8; ++ks) {
            u16x8 v;
#pragma unroll
            for (int j = 0; j < 8; ++j) {
                const int k = 32 * ks + 8 * lg + j;
                v[j] = f2bf(w1[k * 128 + colg]);
            }
            B1[ks][nt] = __builtin_bit_cast(bf16x8, v);
        }
#pragma unroll
        for (int ks = 0; ks < 4; ++ks) {
            u16x8 v;
#pragma unroll
            for (int j = 0; j < 8; ++j) {
                const int k = 32 * ks + 8 * lg + j;
                v[j] = f2bf(w2[k * 128 + colg]);
            }
            B2[ks][nt] = __builtin_bit_cast(bf16x8, v);
        }
    }

    const int ni = tid >> 4;
    const int nt16 = tid & 15;

    for (int tile = blockIdx.x; tile < NN / 16; tile += gridDim.x) {
        __syncthreads();
        const int base = tile * 16;
        {
            const size_t n = (size_t)base + ni;
            *reinterpret_cast<u16x8*>(&A_sh[ni * 264 + nt16 * 8]) =
                *reinterpret_cast<const u16x8*>(hbf + n * 128 + nt16 * 8);
            u16x8 av = cvt8(agg + n * 128 + nt16 * 8);
            *reinterpret_cast<u16x8*>(&A_sh[ni * 264 + 128 + nt16 * 8]) = av;
        }
        if (tid < 48) {
            const int nl = tid / 3, d = tid % 3;
            const size_t n = (size_t)base + nl;
            const float c = (float)(row_ptr[n + 1] - row_ptr[n]);
            pos_out[n * 3 + d] = pos[n * 3 + d] + agg_t[n * 3 + d] / fmaxf(c, 1.f);
        }
        __syncthreads();

        f32x4 acc10 = {0.f, 0.f, 0.f, 0.f};
        f32x4 acc11 = {0.f, 0.f, 0.f, 0.f};
#pragma unroll
        for (int ks = 0; ks < 8; ++ks) {
            bf16x8 a = *reinterpret_cast<const bf16x8*>(&A_sh[l15 * 264 + ks * 32 + lg * 8]);
            acc10 = __builtin_amdgcn_mfma_f32_16x16x32_bf16(a, B1[ks][0], acc10, 0, 0, 0);
            acc11 = __builtin_amdgcn_mfma_f32_16x16x32_bf16(a, B1[ks][1], acc11, 0, 0, 0);
        }
#pragma unroll
        for (int nt = 0; nt < 2; ++nt) {
#pragma unroll
            for (int r = 0; r < 4; ++r) {
                const float x = (nt == 0 ? acc10[r] : acc11[r]) + b1c[nt];
                const int nl = 4 * lg + r;
                const int colg = 32 * w + 16 * nt + l15;
                M1_sh[nl * 136 + colg] = f2bf(fsilu(x));
            }
        }
        __syncthreads();

        f32x4 acc20 = {0.f, 0.f, 0.f, 0.f};
        f32x4 acc21 = {0.f, 0.f, 0.f, 0.f};
#pragma unroll
        for (int ks = 0; ks < 4; ++ks) {
            bf16x8 a = *reinterpret_cast<const bf16x8*>(&M1_sh[l15 * 136 + ks * 32 + lg * 8]);
            acc20 = __builtin_amdgcn_mfma_f32_16x16x32_bf16(a, B2[ks][0], acc20, 0, 0, 0);
            acc21 = __builtin_amdgcn_mfma_f32_16x16x32_bf16(a, B2[ks][1], acc21, 0, 0, 0);
        }
#pragma unroll
        for (int nt = 0; nt < 2; ++nt) {
#pragma unroll
            for (int r = 0; r < 4; ++r) {
                const int nl = 4 * lg + r;
                const int colg = 32 * w + 16 * nt + l15;
                const size_t n = (size_t)base + nl;
                const float hres = bf2f((uint_t)A_sh[nl * 264 + colg]);
                const float y = (nt == 0 ? acc20[r] : acc21[r]) + b2c[nt] + hres;
                hn_out[n * 128 + colg] = y;
            }
        }
    }
}

extern "C" void kernel_launch(void* const* d_in, const int* in_sizes, int n_in,
                              void* d_out, int out_size, void* d_ws, size_t ws_size,
                              hipStream_t stream)
{
    const float* h     = (const float*)d_in[0];
    const float* pos   = (const float*)d_in[1];
    const int*   eidx  = (const int*)d_in[2];
    const float* eattr = (const float*)d_in[3];
    const float* eW1   = (const float*)d_in[4];
    const float* eb1   = (const float*)d_in[5];
    const float* eW2   = (const float*)d_in[6];
    const float* eb2   = (const float*)d_in[7];
    const float* aW    = (const float*)d_in[8];
    const float* ab    = (const float*)d_in[9];
    const float* nW1   = (const float*)d_in[10];
    const float* nb1   = (const float*)d_in[11];
    const float* nW2   = (const float*)d_in[12];
    const float* nb2   = (const float*)d_in[13];
    const float* pW2   = (const float*)d_in[14];

    float* out    = (float*)d_out;
    float* hn_out = out;                                   // N*128
    float* po_out = out + (size_t)NN * 128;                // N*3
    float* m_out  = po_out + (size_t)NN * 3;               // E*128

    // ws layout (bytes)
    char* wsb = (char*)d_ws;
    float* agg_t      = (float*)(wsb + 0);                 //    600,000
    int*   deg        = (int*)  (wsb + 600064);            //    200,000
    int*   row_ptr    = (int*)  (wsb + 800064);            //    200,004
    int*   cursor     = (int*)  (wsb + 1000320);           //    200,000
    int*   bsum       = (int*)  (wsb + 1200320);           //        784
    int*   edge_list  = (int*)  (wsb + 1201152);           //  2,560,000
    int*   row_sorted = (int*)  (wsb + 3761152);           //  2,560,000
    ushort_t* hbf     = (ushort_t*)(wsb + 6321152);        // 12,800,000
    float* agg        = (float*)(wsb + 19121408);          // 25,600,000

    // zero agg_t + deg (contiguous head); agg zeroed inside prep
    hipMemsetAsync(wsb, 0, 800064, stream);

    prep_kernel<<<3200, 256, 0, stream>>>(h, hbf, eidx, deg, agg);
    scan_local_kernel<<<196, 256, 0, stream>>>(deg, row_ptr, bsum);
    scan_bsum_kernel<<<1, 256, 0, stream>>>(bsum);
    scan_fix_kernel<<<196, 256, 0, stream>>>(row_ptr, bsum, cursor);
    scatter_kernel<<<(EE + 255) / 256, 256, 0, stream>>>(eidx, cursor, edge_list, row_sorted);

    egcl_edge_kernel<<<512, 256, 0, stream>>>(hbf, pos, eidx, eattr,
                                              edge_list, row_sorted,
                                              eW1, eb1, eW2, eb2, aW, ab, pW2,
                                              m_out, agg, agg_t);
    egcl_node_kernel<<<512, 256, 0, stream>>>(hbf, agg, agg_t, row_ptr, pos,
                                              nW1, nb1, nW2, nb2,
                                              hn_out, po_out);
}